// Round 6
// baseline (348.158 us; speedup 1.0000x reference)
//
#include <hip/hip_runtime.h>

constexpr int NN = 100000;
constexpr int NE = 800000;
constexpr int SCAN_CHUNK = 512;
constexpr int NBLK = (NN + SCAN_CHUNK - 1) / SCAN_CHUNK;   // 196
constexpr int KTOT = 288;          // 128 (x) + 128 (mean) + 32 (aggE)
constexpr int NOCT = KTOT / 8;     // 36 k-octets

constexpr int CASTX_BLOCKS = (NN * 128 / 8 + 255) / 256;   // 6250
constexpr int HIST_BLOCKS  = 2048;
constexpr int PREP_BLOCKS  = (KTOT * 128 + 128 + 255) / 256; // 145

typedef short bf16x8 __attribute__((ext_vector_type(8)));
typedef float f32x4  __attribute__((ext_vector_type(4)));

__device__ inline ushort f2b(float f) {
    uint u = __builtin_bit_cast(uint, f);
    u += 0x7FFF + ((u >> 16) & 1);
    return (ushort)(u >> 16);
}
__device__ inline float b2f(ushort h) {
    uint u = (uint)h << 16;
    return __builtin_bit_cast(float, u);
}

// ---------------------------------------------------------------------------
// prep body: Btp[NOCT][128][8] bf16 (pre-transposed B) + r vector
__device__ inline void prep_body(int i, const float* __restrict__ Wn,
                                 const float* __restrict__ bn,
                                 const float* __restrict__ We,
                                 const float* __restrict__ be,
                                 const float* __restrict__ Wu,
                                 ushort* __restrict__ Btp, float* __restrict__ r) {
    if (i < KTOT * 128) {
        int K = i >> 7, col = i & 127;
        float v;
        if (K < 128) {
            v = Wu[(size_t)K * 128 + col];
        } else if (K < 256) {
            const float* Wubot = Wu + 128 * 128;
            float s = 0.f;
            for (int m = 0; m < 128; m++)
                s = fmaf(Wn[(K - 128) * 128 + m], Wubot[m * 128 + col], s);
            v = s;
        } else {
            const float* Wubot = Wu + 128 * 128;
            float s = 0.f;
            for (int m = 0; m < 128; m++)
                s = fmaf(We[(K - 256) * 128 + m], Wubot[m * 128 + col], s);
            v = s;
        }
        Btp[(size_t)(K >> 3) * 1024 + col * 8 + (K & 7)] = f2b(v);
    } else if (i < KTOT * 128 + 128) {
        int col = i - KTOT * 128;
        const float* Wubot = Wu + 128 * 128;
        float s = 0.f;
        for (int m = 0; m < 128; m++)
            s = fmaf(bn[m] + be[m], Wubot[m * 128 + col], s);
        r[col] = s;
    }
}

// ---------------------------------------------------------------------------
// merged setup: castx | hist | prep(layer1) | prep(layer2), by block range
__global__ __launch_bounds__(256)
void init_kernel(const float* __restrict__ x, ushort* __restrict__ Xb,
                 const int* __restrict__ dst, int* __restrict__ hist,
                 const float* __restrict__ Wn1, const float* __restrict__ bn1,
                 const float* __restrict__ We1, const float* __restrict__ be1,
                 const float* __restrict__ Wu1,
                 ushort* __restrict__ Btp1, float* __restrict__ r1,
                 const float* __restrict__ Wn2, const float* __restrict__ bn2,
                 const float* __restrict__ We2, const float* __restrict__ be2,
                 const float* __restrict__ Wu2,
                 ushort* __restrict__ Btp2, float* __restrict__ r2) {
    int b = blockIdx.x;
    if (b < CASTX_BLOCKS) {
        size_t i = ((size_t)b * 256 + threadIdx.x) * 8;
        if (i >= (size_t)NN * 128) return;
        float4 v0 = *reinterpret_cast<const float4*>(&x[i]);
        float4 v1 = *reinterpret_cast<const float4*>(&x[i + 4]);
        ushort o[8] = {f2b(v0.x), f2b(v0.y), f2b(v0.z), f2b(v0.w),
                       f2b(v1.x), f2b(v1.y), f2b(v1.z), f2b(v1.w)};
        *reinterpret_cast<bf16x8*>(&Xb[i]) = *reinterpret_cast<bf16x8*>(o);
    } else if (b < CASTX_BLOCKS + HIST_BLOCKS) {
        int bb = b - CASTX_BLOCKS;
        for (int i = bb * 256 + threadIdx.x; i < NE; i += HIST_BLOCKS * 256)
            atomicAdd(&hist[dst[i]], 1);
    } else if (b < CASTX_BLOCKS + HIST_BLOCKS + PREP_BLOCKS) {
        int i = (b - CASTX_BLOCKS - HIST_BLOCKS) * 256 + threadIdx.x;
        prep_body(i, Wn1, bn1, We1, be1, Wu1, Btp1, r1);
    } else {
        int i = (b - CASTX_BLOCKS - HIST_BLOCKS - PREP_BLOCKS) * 256 + threadIdx.x;
        prep_body(i, Wn2, bn2, We2, be2, Wu2, Btp2, r2);
    }
}

// ---------------------------------------------------------------------------
// scan1: per-chunk exclusive scan + chunk totals
__global__ __launch_bounds__(256)
void scan1_kernel(const int* __restrict__ hist, int* __restrict__ rp,
                  int* __restrict__ psum) {
    __shared__ int wsum[4];
    const int b = blockIdx.x, t = threadIdx.x;
    const int i0 = b * SCAN_CHUNK + 2 * t;
    int v0 = (i0     < NN) ? hist[i0]     : 0;
    int v1 = (i0 + 1 < NN) ? hist[i0 + 1] : 0;
    const int ts = v0 + v1;
    const int lane = t & 63, wid = t >> 6;
    int x = ts;
#pragma unroll
    for (int d = 1; d < 64; d <<= 1) {
        int n = __shfl_up(x, d, 64);
        if (lane >= d) x += n;
    }
    if (lane == 63) wsum[wid] = x;
    __syncthreads();
    int woff = (wid > 0 ? wsum[0] : 0) + (wid > 1 ? wsum[1] : 0) +
               (wid > 2 ? wsum[2] : 0);
    int incl = x + woff;
    int excl = incl - ts;
    if (i0     < NN) rp[i0]     = excl;
    if (i0 + 1 < NN) rp[i0 + 1] = excl + v0;
    if (t == 255) psum[b] = incl;
}

// scan2+3 merged: each block reduces psum[0..b) itself, then offsets its chunk
__global__ __launch_bounds__(256)
void scan23_kernel(int* __restrict__ rp, const int* __restrict__ psum) {
    __shared__ int wred[4];
    const int b = blockIdx.x, t = threadIdx.x;
    int val = (t < b) ? psum[t] : 0;    // b <= NBLK-1 < 256
    const int lane = t & 63, wid = t >> 6;
#pragma unroll
    for (int m = 1; m < 64; m <<= 1) val += __shfl_xor(val, m, 64);
    if (lane == 0) wred[wid] = val;
    __syncthreads();
    const int off = wred[0] + wred[1] + wred[2] + wred[3];
    const int i0 = b * SCAN_CHUNK + 2 * t;
    if (i0     < NN) rp[i0]     += off;
    if (i0 + 1 < NN) rp[i0 + 1] += off;
    if (b == 0 && t == 0) rp[NN] = NE;
}

// ---------------------------------------------------------------------------
// placement; hist counted DOWN to zero (no separate fill array)
__global__ __launch_bounds__(256)
void place_kernel(const int* __restrict__ src, const int* __restrict__ dst,
                  const int* __restrict__ rp, int* __restrict__ hist,
                  int* __restrict__ eperm, int* __restrict__ ssrc, int E) {
    for (int e = blockIdx.x * blockDim.x + threadIdx.x; e < E;
         e += gridDim.x * blockDim.x) {
        int d = dst[e];
        int pos = rp[d] + atomicSub(&hist[d], 1) - 1;
        eperm[pos] = e;
        ssrc[pos]  = src[e];
    }
}

// ---------------------------------------------------------------------------
// CSR aggregation, edge-pair scheme, 8 edges per iteration (4 loads in flight)
template<bool DO_EA>
__global__ __launch_bounds__(256)
void agg_kernel(const ushort* __restrict__ Xb, const float* __restrict__ ea,
                const int* __restrict__ eperm, const int* __restrict__ ssrc,
                const int* __restrict__ rp,
                ushort* __restrict__ meanb, ushort* __restrict__ aggEb,
                float* __restrict__ invc) {
    const int wid  = __builtin_amdgcn_readfirstlane(threadIdx.x >> 6);
    const int lane = threadIdx.x & 63;
    const int v = blockIdx.x * 4 + wid;
    if (v >= NN) return;
    const int beg = __builtin_amdgcn_readfirstlane(rp[v]);
    const int end = __builtin_amdgcn_readfirstlane(rp[v + 1]);
    const int half = lane >> 5;
    const int l32  = lane & 31;

    float a0 = 0.f, a1 = 0.f, a2 = 0.f, a3 = 0.f;
    float aE = 0.f;
    int i = beg;
    // ---- 8 edges per iteration (4 pair-loads in flight)
    for (; i + 7 < end; i += 8) {
        int s0 = __builtin_amdgcn_readfirstlane(ssrc[i]);
        int s1 = __builtin_amdgcn_readfirstlane(ssrc[i + 1]);
        int s2 = __builtin_amdgcn_readfirstlane(ssrc[i + 2]);
        int s3 = __builtin_amdgcn_readfirstlane(ssrc[i + 3]);
        int s4 = __builtin_amdgcn_readfirstlane(ssrc[i + 4]);
        int s5 = __builtin_amdgcn_readfirstlane(ssrc[i + 5]);
        int s6 = __builtin_amdgcn_readfirstlane(ssrc[i + 6]);
        int s7 = __builtin_amdgcn_readfirstlane(ssrc[i + 7]);
        int sA = half ? s1 : s0, sB = half ? s3 : s2;
        int sC = half ? s5 : s4, sD = half ? s7 : s6;
        uint2 qA = *reinterpret_cast<const uint2*>(Xb + (size_t)sA * 128 + l32 * 4);
        uint2 qB = *reinterpret_cast<const uint2*>(Xb + (size_t)sB * 128 + l32 * 4);
        uint2 qC = *reinterpret_cast<const uint2*>(Xb + (size_t)sC * 128 + l32 * 4);
        uint2 qD = *reinterpret_cast<const uint2*>(Xb + (size_t)sD * 128 + l32 * 4);
        if (DO_EA) {
            int e0 = __builtin_amdgcn_readfirstlane(eperm[i]);
            int e1 = __builtin_amdgcn_readfirstlane(eperm[i + 1]);
            int e2 = __builtin_amdgcn_readfirstlane(eperm[i + 2]);
            int e3 = __builtin_amdgcn_readfirstlane(eperm[i + 3]);
            int e4 = __builtin_amdgcn_readfirstlane(eperm[i + 4]);
            int e5 = __builtin_amdgcn_readfirstlane(eperm[i + 5]);
            int e6 = __builtin_amdgcn_readfirstlane(eperm[i + 6]);
            int e7 = __builtin_amdgcn_readfirstlane(eperm[i + 7]);
            int eA = half ? e1 : e0, eB = half ? e3 : e2;
            int eC = half ? e5 : e4, eD = half ? e7 : e6;
            float fA = ea[(size_t)eA * 32 + l32];
            float fB = ea[(size_t)eB * 32 + l32];
            float fC = ea[(size_t)eC * 32 + l32];
            float fD = ea[(size_t)eD * 32 + l32];
            aE += (fA + fB) + (fC + fD);
        }
        a0 += (b2f((ushort)qA.x) + b2f((ushort)qB.x)) +
              (b2f((ushort)qC.x) + b2f((ushort)qD.x));
        a1 += (b2f((ushort)(qA.x >> 16)) + b2f((ushort)(qB.x >> 16))) +
              (b2f((ushort)(qC.x >> 16)) + b2f((ushort)(qD.x >> 16)));
        a2 += (b2f((ushort)qA.y) + b2f((ushort)qB.y)) +
              (b2f((ushort)qC.y) + b2f((ushort)qD.y));
        a3 += (b2f((ushort)(qA.y >> 16)) + b2f((ushort)(qB.y >> 16))) +
              (b2f((ushort)(qC.y >> 16)) + b2f((ushort)(qD.y >> 16)));
    }
    // ---- 4-edge step
    if (i + 3 < end) {
        int s0 = __builtin_amdgcn_readfirstlane(ssrc[i]);
        int s1 = __builtin_amdgcn_readfirstlane(ssrc[i + 1]);
        int s2 = __builtin_amdgcn_readfirstlane(ssrc[i + 2]);
        int s3 = __builtin_amdgcn_readfirstlane(ssrc[i + 3]);
        int sA = half ? s1 : s0, sB = half ? s3 : s2;
        uint2 qA = *reinterpret_cast<const uint2*>(Xb + (size_t)sA * 128 + l32 * 4);
        uint2 qB = *reinterpret_cast<const uint2*>(Xb + (size_t)sB * 128 + l32 * 4);
        if (DO_EA) {
            int e0 = __builtin_amdgcn_readfirstlane(eperm[i]);
            int e1 = __builtin_amdgcn_readfirstlane(eperm[i + 1]);
            int e2 = __builtin_amdgcn_readfirstlane(eperm[i + 2]);
            int e3 = __builtin_amdgcn_readfirstlane(eperm[i + 3]);
            int eA = half ? e1 : e0, eB = half ? e3 : e2;
            aE += ea[(size_t)eA * 32 + l32] + ea[(size_t)eB * 32 + l32];
        }
        a0 += b2f((ushort)qA.x) + b2f((ushort)qB.x);
        a1 += b2f((ushort)(qA.x >> 16)) + b2f((ushort)(qB.x >> 16));
        a2 += b2f((ushort)qA.y) + b2f((ushort)qB.y);
        a3 += b2f((ushort)(qA.y >> 16)) + b2f((ushort)(qB.y >> 16));
        i += 4;
    }
    // ---- 2-edge step
    if (i + 1 < end) {
        int s0 = __builtin_amdgcn_readfirstlane(ssrc[i]);
        int s1 = __builtin_amdgcn_readfirstlane(ssrc[i + 1]);
        int sA = half ? s1 : s0;
        uint2 qA = *reinterpret_cast<const uint2*>(Xb + (size_t)sA * 128 + l32 * 4);
        if (DO_EA) {
            int e0 = __builtin_amdgcn_readfirstlane(eperm[i]);
            int e1 = __builtin_amdgcn_readfirstlane(eperm[i + 1]);
            int eA = half ? e1 : e0;
            aE += ea[(size_t)eA * 32 + l32];
        }
        a0 += b2f((ushort)qA.x);
        a1 += b2f((ushort)(qA.x >> 16));
        a2 += b2f((ushort)qA.y);
        a3 += b2f((ushort)(qA.y >> 16));
        i += 2;
    }
    // ---- 1-edge tail (half 0 only)
    if (i < end) {
        int s0 = __builtin_amdgcn_readfirstlane(ssrc[i]);
        if (half == 0) {
            uint2 qA = *reinterpret_cast<const uint2*>(Xb + (size_t)s0 * 128 + l32 * 4);
            a0 += b2f((ushort)qA.x);
            a1 += b2f((ushort)(qA.x >> 16));
            a2 += b2f((ushort)qA.y);
            a3 += b2f((ushort)(qA.y >> 16));
            if (DO_EA) {
                int e0 = __builtin_amdgcn_readfirstlane(eperm[i]);
                aE += ea[(size_t)e0 * 32 + l32];
            }
        }
    }
    // ---- combine halves
    a0 += __shfl_xor(a0, 32, 64);
    a1 += __shfl_xor(a1, 32, 64);
    a2 += __shfl_xor(a2, 32, 64);
    a3 += __shfl_xor(a3, 32, 64);
    if (DO_EA) aE += __shfl_xor(aE, 32, 64);

    float inv = (end > beg) ? 1.0f / (float)(end - beg) : 0.0f;
    if (half == 0) {
        uint lo = (uint)f2b(a0 * inv) | ((uint)f2b(a1 * inv) << 16);
        uint hi = (uint)f2b(a2 * inv) | ((uint)f2b(a3 * inv) << 16);
        *reinterpret_cast<uint2*>(meanb + (size_t)v * 128 + l32 * 4) =
            make_uint2(lo, hi);
        if (DO_EA) aggEb[(size_t)v * 32 + l32] = f2b(aE * inv);
    }
    if (DO_EA && lane == 0) invc[v] = inv;
}

// ---------------------------------------------------------------------------
// fused MFMA GEMM, 128x128 tile: C = LN(relu(Abig @ B + bu + has*r), g, beta)
// 4 waves in 2x2 grid, each wave 64 rows x 64 cols = 4x4 16x16x32 frags.
template<bool OUT_BF16>
__global__ __launch_bounds__(256)
void gemmF_kernel(const ushort* __restrict__ Xb, const ushort* __restrict__ meanb,
                  const ushort* __restrict__ aggEb, const float* __restrict__ invc,
                  const ushort* __restrict__ Btp, const float* __restrict__ r,
                  const float* __restrict__ bu, const float* __restrict__ g,
                  const float* __restrict__ beta,
                  float* __restrict__ Cf, ushort* __restrict__ Cb, int M) {
    __shared__ ushort Als[4][128][8];   // 8KB
    __shared__ ushort Bls[4][128][8];   // 8KB
    __shared__ float ps[2][128], ps2[2][128];

    const int tid = threadIdx.x;
    const int wid = tid >> 6, lane = tid & 63;
    const int wr = wid >> 1, wc = wid & 1;
    const int lo4 = lane >> 4, li = lane & 15;
    const int brow = blockIdx.x * 128;

    f32x4 acc[4][4];
#pragma unroll
    for (int fr = 0; fr < 4; fr++)
#pragma unroll
        for (int fc = 0; fc < 4; fc++) acc[fr][fc] = (f32x4)0.f;

    for (int step = 0; step < 9; step++) {
        // ---- stage A: 128 rows x 4 octets (2 slots/thread)
#pragma unroll
        for (int h = 0; h < 2; h++) {
            int u = tid + h * 256;
            int row = u & 127, kc = u >> 7;
            int kg = step * 4 + kc;
            int grow = brow + row;
            bf16x8 v = (bf16x8)0;
            if (grow < M) {
                if (kg < 16)
                    v = *reinterpret_cast<const bf16x8*>(Xb + (size_t)grow * 128 + kg * 8);
                else if (kg < 32)
                    v = *reinterpret_cast<const bf16x8*>(meanb + (size_t)grow * 128 + (kg - 16) * 8);
                else
                    v = *reinterpret_cast<const bf16x8*>(aggEb + (size_t)grow * 32 + (kg - 32) * 8);
            }
            *reinterpret_cast<bf16x8*>(&Als[kc][row][0]) = v;
        }
        // ---- stage B: 4 octets x 128 cols (2 slots/thread)
#pragma unroll
        for (int h = 0; h < 2; h++) {
            int u = tid + h * 256;
            int kcl = u >> 7, col = u & 127;
            *reinterpret_cast<bf16x8*>(&Bls[kcl][col][0]) =
                *reinterpret_cast<const bf16x8*>(
                    Btp + ((size_t)(step * 4 + kcl) * 128 + col) * 8);
        }
        __syncthreads();

        bf16x8 af[4], bfr[4];
#pragma unroll
        for (int fr = 0; fr < 4; fr++)
            af[fr] = *reinterpret_cast<const bf16x8*>(&Als[lo4][wr * 64 + fr * 16 + li][0]);
#pragma unroll
        for (int fc = 0; fc < 4; fc++)
            bfr[fc] = *reinterpret_cast<const bf16x8*>(&Bls[lo4][wc * 64 + fc * 16 + li][0]);
#pragma unroll
        for (int fr = 0; fr < 4; fr++)
#pragma unroll
            for (int fc = 0; fc < 4; fc++)
                acc[fr][fc] = __builtin_amdgcn_mfma_f32_16x16x32_bf16(
                    af[fr], bfr[fc], acc[fr][fc], 0, 0, 0);
        __syncthreads();
    }

    // ---- epilogue: bias + has*r, relu, cross-wave layernorm, store
    float bu8[4], r8[4], g8[4], be8[4];
#pragma unroll
    for (int fc = 0; fc < 4; fc++) {
        int col = wc * 64 + fc * 16 + li;
        bu8[fc] = bu[col]; r8[fc] = r[col]; g8[fc] = g[col]; be8[fc] = beta[col];
    }

    float sv[4][4], s2v[4][4];
#pragma unroll
    for (int fr = 0; fr < 4; fr++)
#pragma unroll
        for (int j = 0; j < 4; j++) {
            int gr = brow + wr * 64 + fr * 16 + lo4 * 4 + j;
            float hv = 0.f;
            if (gr < M) hv = (invc[gr] > 0.f) ? 1.f : 0.f;
            float s = 0.f, s2 = 0.f;
#pragma unroll
            for (int fc = 0; fc < 4; fc++) {
                float val = acc[fr][fc][j] + bu8[fc] + hv * r8[fc];
                val = fmaxf(val, 0.f);
                acc[fr][fc][j] = val;
                s += val; s2 += val * val;
            }
#pragma unroll
            for (int m = 1; m < 16; m <<= 1) {
                s  += __shfl_xor(s, m, 64);
                s2 += __shfl_xor(s2, m, 64);
            }
            sv[fr][j] = s; s2v[fr][j] = s2;
        }

    if (li == 0) {
#pragma unroll
        for (int fr = 0; fr < 4; fr++)
#pragma unroll
            for (int j = 0; j < 4; j++) {
                int row128 = wr * 64 + fr * 16 + lo4 * 4 + j;
                ps[wc][row128]  = sv[fr][j];
                ps2[wc][row128] = s2v[fr][j];
            }
    }
    __syncthreads();

#pragma unroll
    for (int fr = 0; fr < 4; fr++)
#pragma unroll
        for (int j = 0; j < 4; j++) {
            int row128 = wr * 64 + fr * 16 + lo4 * 4 + j;
            int gr = brow + row128;
            float s  = sv[fr][j]  + ps[1 - wc][row128];
            float s2 = s2v[fr][j] + ps2[1 - wc][row128];
            float mean = s * (1.0f / 128.0f);
            float var  = s2 * (1.0f / 128.0f) - mean * mean;
            float rstd = rsqrtf(var + 1e-5f);
            if (gr < M) {
#pragma unroll
                for (int fc = 0; fc < 4; fc++) {
                    int col = wc * 64 + fc * 16 + li;
                    float o = (acc[fr][fc][j] - mean) * rstd * g8[fc] + be8[fc];
                    if (OUT_BF16) Cb[(size_t)gr * 128 + col] = f2b(o);
                    else          Cf[(size_t)gr * 128 + col] = o;
                }
            }
        }
}

// ---------------------------------------------------------------------------
extern "C" void kernel_launch(void* const* d_in, const int* in_sizes, int n_in,
                              void* d_out, int out_size, void* d_ws, size_t ws_size,
                              hipStream_t stream)
{
    const float* x    = (const float*)d_in[0];
    const int*   ei   = (const int*)d_in[1];
    const float* ea   = (const float*)d_in[2];
    const float* Wn1  = (const float*)d_in[3];
    const float* bn1  = (const float*)d_in[4];
    const float* We1  = (const float*)d_in[5];
    const float* be1  = (const float*)d_in[6];
    const float* Wu1  = (const float*)d_in[7];
    const float* bu1  = (const float*)d_in[8];
    const float* g1   = (const float*)d_in[9];
    const float* beta1= (const float*)d_in[10];
    const float* Wn2  = (const float*)d_in[11];
    const float* bn2  = (const float*)d_in[12];
    const float* We2  = (const float*)d_in[13];
    const float* be2  = (const float*)d_in[14];
    const float* Wu2  = (const float*)d_in[15];
    const float* bu2  = (const float*)d_in[16];
    const float* g2   = (const float*)d_in[17];
    const float* beta2= (const float*)d_in[18];

    const int* srcI = ei;
    const int* dstI = ei + NE;
    float* out = (float*)d_out;

    // ---- workspace layout
    float* invc = (float*)d_ws;                        // N
    int*   rp   = (int*)(invc + NN);                   // N+1
    int*   hist = rp + NN + 1;                         // N
    int*   psum = hist + NN;                           // 256
    int*   eperm= psum + 256;                          // E
    int*   ssrc = eperm + NE;                          // E
    uintptr_t base = ((uintptr_t)(ssrc + NE) + 15) & ~(uintptr_t)15;
    ushort* Xb    = (ushort*)base;                     // N*128 (also h1 bf16)
    ushort* meanb = Xb + (size_t)NN * 128;             // N*128
    ushort* aggEb = meanb + (size_t)NN * 128;          // N*32
    ushort* Btp1  = aggEb + (size_t)NN * 32;           // 36*128*8
    ushort* Btp2  = Btp1 + NOCT * 1024;
    float*  r1    = (float*)(Btp2 + NOCT * 1024);      // 128
    float*  r2    = r1 + 128;

    const int gemm_grid = (NN + 127) / 128;

    // ---- setup: zero hist, then merged castx|hist|prep1|prep2
    hipMemsetAsync(hist, 0, NN * sizeof(int), stream);
    init_kernel<<<CASTX_BLOCKS + HIST_BLOCKS + 2 * PREP_BLOCKS, 256, 0, stream>>>(
        x, Xb, dstI, hist,
        Wn1, bn1, We1, be1, Wu1, Btp1, r1,
        Wn2, bn2, We2, be2, Wu2, Btp2, r2);

    // ---- CSR build
    scan1_kernel<<<NBLK, 256, 0, stream>>>(hist, rp, psum);
    scan23_kernel<<<NBLK, 256, 0, stream>>>(rp, psum);
    place_kernel<<<2048, 256, 0, stream>>>(srcI, dstI, rp, hist, eperm, ssrc, NE);

    // ---- layer 1 (computes meanb + layer-invariant aggEb/invc)
    agg_kernel<true><<<(NN + 3) / 4, 256, 0, stream>>>(Xb, ea, eperm, ssrc, rp,
                                                       meanb, aggEb, invc);
    gemmF_kernel<true><<<gemm_grid, 256, 0, stream>>>(
        Xb, meanb, aggEb, invc, Btp1, r1, bu1, g1, beta1, nullptr, Xb, NN);

    // ---- layer 2 (Xb now holds h1 bf16; aggEb/invc reused)
    agg_kernel<false><<<(NN + 3) / 4, 256, 0, stream>>>(Xb, ea, eperm, ssrc, rp,
                                                        meanb, aggEb, invc);
    gemmF_kernel<false><<<gemm_grid, 256, 0, stream>>>(
        Xb, meanb, aggEb, invc, Btp2, r2, bu2, g2, beta2, out, nullptr, NN);
}

// Round 7
// 298.164 us; speedup vs baseline: 1.1677x; 1.1677x over previous
//
#include <hip/hip_runtime.h>

constexpr int NN = 100000;
constexpr int NE = 800000;
constexpr int SCAN_CHUNK = 512;
constexpr int NBLK = (NN + SCAN_CHUNK - 1) / SCAN_CHUNK;   // 196
constexpr int KTOT = 288;          // 128 (x) + 128 (mean) + 32 (aggE)
constexpr int NOCT = KTOT / 8;     // 36 k-octets

constexpr int CASTX_BLOCKS = (NN * 128 / 8 + 255) / 256;   // 6250
constexpr int HIST_BLOCKS  = 2048;
constexpr int PREP_BLOCKS  = (KTOT * 128 + 128 + 255) / 256; // 145

typedef short bf16x8 __attribute__((ext_vector_type(8)));
typedef float f32x4  __attribute__((ext_vector_type(4)));

__device__ inline ushort f2b(float f) {
    uint u = __builtin_bit_cast(uint, f);
    u += 0x7FFF + ((u >> 16) & 1);
    return (ushort)(u >> 16);
}
__device__ inline float b2f(ushort h) {
    uint u = (uint)h << 16;
    return __builtin_bit_cast(float, u);
}
// low/high bf16 of a packed uint -> float (1 VALU op each)
__device__ inline float b2f_lo(uint q) { return __builtin_bit_cast(float, q << 16); }
__device__ inline float b2f_hi(uint q) { return __builtin_bit_cast(float, q & 0xffff0000u); }

// ---------------------------------------------------------------------------
// prep body: Btp[NOCT][128][8] bf16 (pre-transposed B) + r vector
__device__ inline void prep_body(int i, const float* __restrict__ Wn,
                                 const float* __restrict__ bn,
                                 const float* __restrict__ We,
                                 const float* __restrict__ be,
                                 const float* __restrict__ Wu,
                                 ushort* __restrict__ Btp, float* __restrict__ r) {
    if (i < KTOT * 128) {
        int K = i >> 7, col = i & 127;
        float v;
        if (K < 128) {
            v = Wu[(size_t)K * 128 + col];
        } else if (K < 256) {
            const float* Wubot = Wu + 128 * 128;
            float s = 0.f;
            for (int m = 0; m < 128; m++)
                s = fmaf(Wn[(K - 128) * 128 + m], Wubot[m * 128 + col], s);
            v = s;
        } else {
            const float* Wubot = Wu + 128 * 128;
            float s = 0.f;
            for (int m = 0; m < 128; m++)
                s = fmaf(We[(K - 256) * 128 + m], Wubot[m * 128 + col], s);
            v = s;
        }
        Btp[(size_t)(K >> 3) * 1024 + col * 8 + (K & 7)] = f2b(v);
    } else if (i < KTOT * 128 + 128) {
        int col = i - KTOT * 128;
        const float* Wubot = Wu + 128 * 128;
        float s = 0.f;
        for (int m = 0; m < 128; m++)
            s = fmaf(bn[m] + be[m], Wubot[m * 128 + col], s);
        r[col] = s;
    }
}

// ---------------------------------------------------------------------------
// merged setup: castx | hist | prep(layer1) | prep(layer2), by block range
__global__ __launch_bounds__(256)
void init_kernel(const float* __restrict__ x, ushort* __restrict__ Xb,
                 const int* __restrict__ dst, int* __restrict__ hist,
                 const float* __restrict__ Wn1, const float* __restrict__ bn1,
                 const float* __restrict__ We1, const float* __restrict__ be1,
                 const float* __restrict__ Wu1,
                 ushort* __restrict__ Btp1, float* __restrict__ r1,
                 const float* __restrict__ Wn2, const float* __restrict__ bn2,
                 const float* __restrict__ We2, const float* __restrict__ be2,
                 const float* __restrict__ Wu2,
                 ushort* __restrict__ Btp2, float* __restrict__ r2) {
    int b = blockIdx.x;
    if (b < CASTX_BLOCKS) {
        size_t i = ((size_t)b * 256 + threadIdx.x) * 8;
        if (i >= (size_t)NN * 128) return;
        float4 v0 = *reinterpret_cast<const float4*>(&x[i]);
        float4 v1 = *reinterpret_cast<const float4*>(&x[i + 4]);
        ushort o[8] = {f2b(v0.x), f2b(v0.y), f2b(v0.z), f2b(v0.w),
                       f2b(v1.x), f2b(v1.y), f2b(v1.z), f2b(v1.w)};
        *reinterpret_cast<bf16x8*>(&Xb[i]) = *reinterpret_cast<bf16x8*>(o);
    } else if (b < CASTX_BLOCKS + HIST_BLOCKS) {
        int bb = b - CASTX_BLOCKS;
        for (int i = bb * 256 + threadIdx.x; i < NE; i += HIST_BLOCKS * 256)
            atomicAdd(&hist[dst[i]], 1);
    } else if (b < CASTX_BLOCKS + HIST_BLOCKS + PREP_BLOCKS) {
        int i = (b - CASTX_BLOCKS - HIST_BLOCKS) * 256 + threadIdx.x;
        prep_body(i, Wn1, bn1, We1, be1, Wu1, Btp1, r1);
    } else {
        int i = (b - CASTX_BLOCKS - HIST_BLOCKS - PREP_BLOCKS) * 256 + threadIdx.x;
        prep_body(i, Wn2, bn2, We2, be2, Wu2, Btp2, r2);
    }
}

// ---------------------------------------------------------------------------
// scan1: per-chunk exclusive scan + chunk totals
__global__ __launch_bounds__(256)
void scan1_kernel(const int* __restrict__ hist, int* __restrict__ rp,
                  int* __restrict__ psum) {
    __shared__ int wsum[4];
    const int b = blockIdx.x, t = threadIdx.x;
    const int i0 = b * SCAN_CHUNK + 2 * t;
    int v0 = (i0     < NN) ? hist[i0]     : 0;
    int v1 = (i0 + 1 < NN) ? hist[i0 + 1] : 0;
    const int ts = v0 + v1;
    const int lane = t & 63, wid = t >> 6;
    int x = ts;
#pragma unroll
    for (int d = 1; d < 64; d <<= 1) {
        int n = __shfl_up(x, d, 64);
        if (lane >= d) x += n;
    }
    if (lane == 63) wsum[wid] = x;
    __syncthreads();
    int woff = (wid > 0 ? wsum[0] : 0) + (wid > 1 ? wsum[1] : 0) +
               (wid > 2 ? wsum[2] : 0);
    int incl = x + woff;
    int excl = incl - ts;
    if (i0     < NN) rp[i0]     = excl;
    if (i0 + 1 < NN) rp[i0 + 1] = excl + v0;
    if (t == 255) psum[b] = incl;
}

// scan2+3 merged: each block reduces psum[0..b) itself, then offsets its chunk
__global__ __launch_bounds__(256)
void scan23_kernel(int* __restrict__ rp, const int* __restrict__ psum) {
    __shared__ int wred[4];
    const int b = blockIdx.x, t = threadIdx.x;
    int val = (t < b) ? psum[t] : 0;    // b <= NBLK-1 < 256
    const int lane = t & 63, wid = t >> 6;
#pragma unroll
    for (int m = 1; m < 64; m <<= 1) val += __shfl_xor(val, m, 64);
    if (lane == 0) wred[wid] = val;
    __syncthreads();
    const int off = wred[0] + wred[1] + wred[2] + wred[3];
    const int i0 = b * SCAN_CHUNK + 2 * t;
    if (i0     < NN) rp[i0]     += off;
    if (i0 + 1 < NN) rp[i0 + 1] += off;
    if (b == 0 && t == 0) rp[NN] = NE;
}

// ---------------------------------------------------------------------------
// placement; hist counted DOWN to zero (no separate fill array)
__global__ __launch_bounds__(256)
void place_kernel(const int* __restrict__ src, const int* __restrict__ dst,
                  const int* __restrict__ rp, int* __restrict__ hist,
                  int* __restrict__ eperm, int* __restrict__ ssrc, int E) {
    for (int e = blockIdx.x * blockDim.x + threadIdx.x; e < E;
         e += gridDim.x * blockDim.x) {
        int d = dst[e];
        int pos = rp[d] + atomicSub(&hist[d], 1) - 1;
        eperm[pos] = e;
        ssrc[pos]  = src[e];
    }
}

// ---------------------------------------------------------------------------
// CSR aggregation, quarter scheme: 16 lanes per edge, 4 edges per instruction.
// Per iteration: 8 edges = 2 x dwordx4 (Xb) + 2 x dwordx2 (ea), all independent.
// Tail edges handled by clamping index to end-1 (same cache line, no extra
// HBM traffic) and fma-masking the contribution.
template<bool DO_EA>
__global__ __launch_bounds__(256)
void agg_kernel(const ushort* __restrict__ Xb, const float* __restrict__ ea,
                const int* __restrict__ eperm, const int* __restrict__ ssrc,
                const int* __restrict__ rp,
                ushort* __restrict__ meanb, ushort* __restrict__ aggEb,
                float* __restrict__ invc) {
    const int wid  = threadIdx.x >> 6;
    const int lane = threadIdx.x & 63;
    const int v = blockIdx.x * 4 + wid;
    if (v >= NN) return;
    const int beg = rp[v], end = rp[v + 1];
    const int q = lane >> 4, l16 = lane & 15;

    float acc[8] = {0.f, 0.f, 0.f, 0.f, 0.f, 0.f, 0.f, 0.f};
    float aE0 = 0.f, aE1 = 0.f;

    if (beg < end) {
        const int last = end - 1;
        for (int i = beg; i < end; i += 8) {
            int iA = i + q, iB = i + 4 + q;
            int cA = min(iA, last), cB = min(iB, last);
            float mA = (iA < end) ? 1.f : 0.f;
            float mB = (iB < end) ? 1.f : 0.f;
            int sA = ssrc[cA], sB = ssrc[cB];
            uint4 qA = *reinterpret_cast<const uint4*>(Xb + (size_t)sA * 128 + l16 * 8);
            uint4 qB = *reinterpret_cast<const uint4*>(Xb + (size_t)sB * 128 + l16 * 8);
            if (DO_EA) {
                int eA = eperm[cA], eB = eperm[cB];
                float2 fA = *reinterpret_cast<const float2*>(ea + (size_t)eA * 32 + l16 * 2);
                float2 fB = *reinterpret_cast<const float2*>(ea + (size_t)eB * 32 + l16 * 2);
                aE0 = fmaf(mA, fA.x, aE0); aE1 = fmaf(mA, fA.y, aE1);
                aE0 = fmaf(mB, fB.x, aE0); aE1 = fmaf(mB, fB.y, aE1);
            }
            acc[0] = fmaf(mA, b2f_lo(qA.x), acc[0]);
            acc[1] = fmaf(mA, b2f_hi(qA.x), acc[1]);
            acc[2] = fmaf(mA, b2f_lo(qA.y), acc[2]);
            acc[3] = fmaf(mA, b2f_hi(qA.y), acc[3]);
            acc[4] = fmaf(mA, b2f_lo(qA.z), acc[4]);
            acc[5] = fmaf(mA, b2f_hi(qA.z), acc[5]);
            acc[6] = fmaf(mA, b2f_lo(qA.w), acc[6]);
            acc[7] = fmaf(mA, b2f_hi(qA.w), acc[7]);
            acc[0] = fmaf(mB, b2f_lo(qB.x), acc[0]);
            acc[1] = fmaf(mB, b2f_hi(qB.x), acc[1]);
            acc[2] = fmaf(mB, b2f_lo(qB.y), acc[2]);
            acc[3] = fmaf(mB, b2f_hi(qB.y), acc[3]);
            acc[4] = fmaf(mB, b2f_lo(qB.z), acc[4]);
            acc[5] = fmaf(mB, b2f_hi(qB.z), acc[5]);
            acc[6] = fmaf(mB, b2f_lo(qB.w), acc[6]);
            acc[7] = fmaf(mB, b2f_hi(qB.w), acc[7]);
        }
    }
    // combine quarters (lanes sharing l16)
#pragma unroll
    for (int k = 0; k < 8; k++) {
        acc[k] += __shfl_xor(acc[k], 16, 64);
        acc[k] += __shfl_xor(acc[k], 32, 64);
    }
    if (DO_EA) {
        aE0 += __shfl_xor(aE0, 16, 64); aE0 += __shfl_xor(aE0, 32, 64);
        aE1 += __shfl_xor(aE1, 16, 64); aE1 += __shfl_xor(aE1, 32, 64);
    }

    float inv = (end > beg) ? 1.0f / (float)(end - beg) : 0.0f;
    if (q == 0) {
        uint4 o;
        o.x = (uint)f2b(acc[0] * inv) | ((uint)f2b(acc[1] * inv) << 16);
        o.y = (uint)f2b(acc[2] * inv) | ((uint)f2b(acc[3] * inv) << 16);
        o.z = (uint)f2b(acc[4] * inv) | ((uint)f2b(acc[5] * inv) << 16);
        o.w = (uint)f2b(acc[6] * inv) | ((uint)f2b(acc[7] * inv) << 16);
        *reinterpret_cast<uint4*>(meanb + (size_t)v * 128 + l16 * 8) = o;
        if (DO_EA) {
            uint p = (uint)f2b(aE0 * inv) | ((uint)f2b(aE1 * inv) << 16);
            *reinterpret_cast<uint*>(aggEb + (size_t)v * 32 + l16 * 2) = p;
        }
    }
    if (DO_EA && lane == 0) invc[v] = inv;
}

// ---------------------------------------------------------------------------
// fused MFMA GEMM, 64-row tile (round-5 known-good config):
// C = LN(relu(Abig @ B + bu + has*r), g, beta)
template<bool OUT_BF16>
__global__ __launch_bounds__(256)
void gemmF_kernel(const ushort* __restrict__ Xb, const ushort* __restrict__ meanb,
                  const ushort* __restrict__ aggEb, const float* __restrict__ invc,
                  const ushort* __restrict__ Btp, const float* __restrict__ r,
                  const float* __restrict__ bu, const float* __restrict__ g,
                  const float* __restrict__ beta,
                  float* __restrict__ Cf, ushort* __restrict__ Cb, int M) {
    __shared__ ushort Als[4][64][8];
    __shared__ ushort Bls[4][128][8];
    __shared__ float ps[2][64], ps2[2][64];

    const int tid = threadIdx.x;
    const int wid = tid >> 6, lane = tid & 63;
    const int wr = wid >> 1, wc = wid & 1;
    const int lo4 = lane >> 4, li = lane & 15;
    const int brow = blockIdx.x * 64;

    f32x4 acc[2][4];
#pragma unroll
    for (int fr = 0; fr < 2; fr++)
#pragma unroll
        for (int fc = 0; fc < 4; fc++) acc[fr][fc] = (f32x4)0.f;

    const int arow = tid & 63;
    const int akc  = tid >> 6;
    const int grow = brow + arow;

    for (int step = 0; step < 9; step++) {
        {
            int kg = step * 4 + akc;
            bf16x8 v = (bf16x8)0;
            if (grow < M) {
                if (kg < 16)
                    v = *reinterpret_cast<const bf16x8*>(Xb + (size_t)grow * 128 + kg * 8);
                else if (kg < 32)
                    v = *reinterpret_cast<const bf16x8*>(meanb + (size_t)grow * 128 + (kg - 16) * 8);
                else
                    v = *reinterpret_cast<const bf16x8*>(aggEb + (size_t)grow * 32 + (kg - 32) * 8);
            }
            *reinterpret_cast<bf16x8*>(&Als[akc][arow][0]) = v;
        }
#pragma unroll
        for (int h = 0; h < 2; h++) {
            int u = tid + h * 256;
            int kcl = u >> 7, col = u & 127;
            *reinterpret_cast<bf16x8*>(&Bls[kcl][col][0]) =
                *reinterpret_cast<const bf16x8*>(
                    Btp + ((size_t)(step * 4 + kcl) * 128 + col) * 8);
        }
        __syncthreads();

        bf16x8 a0 = *reinterpret_cast<const bf16x8*>(&Als[lo4][wr * 32 + li][0]);
        bf16x8 a1 = *reinterpret_cast<const bf16x8*>(&Als[lo4][wr * 32 + 16 + li][0]);
#pragma unroll
        for (int fc = 0; fc < 4; fc++) {
            bf16x8 b = *reinterpret_cast<const bf16x8*>(&Bls[lo4][wc * 64 + fc * 16 + li][0]);
            acc[0][fc] = __builtin_amdgcn_mfma_f32_16x16x32_bf16(a0, b, acc[0][fc], 0, 0, 0);
            acc[1][fc] = __builtin_amdgcn_mfma_f32_16x16x32_bf16(a1, b, acc[1][fc], 0, 0, 0);
        }
        __syncthreads();
    }

    float bu8[4], r8[4], g8[4], be8[4];
#pragma unroll
    for (int fc = 0; fc < 4; fc++) {
        int col = wc * 64 + fc * 16 + li;
        bu8[fc] = bu[col]; r8[fc] = r[col]; g8[fc] = g[col]; be8[fc] = beta[col];
    }

    float sv[2][4], s2v[2][4];
#pragma unroll
    for (int fr = 0; fr < 2; fr++)
#pragma unroll
        for (int j = 0; j < 4; j++) {
            int gr = brow + wr * 32 + fr * 16 + lo4 * 4 + j;
            float hv = 0.f;
            if (gr < M) hv = (invc[gr] > 0.f) ? 1.f : 0.f;
            float s = 0.f, s2 = 0.f;
#pragma unroll
            for (int fc = 0; fc < 4; fc++) {
                float val = acc[fr][fc][j] + bu8[fc] + hv * r8[fc];
                val = fmaxf(val, 0.f);
                acc[fr][fc][j] = val;
                s += val; s2 += val * val;
            }
#pragma unroll
            for (int m = 1; m < 16; m <<= 1) {
                s  += __shfl_xor(s, m, 64);
                s2 += __shfl_xor(s2, m, 64);
            }
            sv[fr][j] = s; s2v[fr][j] = s2;
        }

    if (li == 0) {
#pragma unroll
        for (int fr = 0; fr < 2; fr++)
#pragma unroll
            for (int j = 0; j < 4; j++) {
                int row64 = wr * 32 + fr * 16 + lo4 * 4 + j;
                ps[wc][row64]  = sv[fr][j];
                ps2[wc][row64] = s2v[fr][j];
            }
    }
    __syncthreads();

#pragma unroll
    for (int fr = 0; fr < 2; fr++)
#pragma unroll
        for (int j = 0; j < 4; j++) {
            int row64 = wr * 32 + fr * 16 + lo4 * 4 + j;
            int gr = brow + row64;
            float s  = sv[fr][j]  + ps[1 - wc][row64];
            float s2 = s2v[fr][j] + ps2[1 - wc][row64];
            float mean = s * (1.0f / 128.0f);
            float var  = s2 * (1.0f / 128.0f) - mean * mean;
            float rstd = rsqrtf(var + 1e-5f);
            if (gr < M) {
#pragma unroll
                for (int fc = 0; fc < 4; fc++) {
                    int col = wc * 64 + fc * 16 + li;
                    float o = (acc[fr][fc][j] - mean) * rstd * g8[fc] + be8[fc];
                    if (OUT_BF16) Cb[(size_t)gr * 128 + col] = f2b(o);
                    else          Cf[(size_t)gr * 128 + col] = o;
                }
            }
        }
}

// ---------------------------------------------------------------------------
extern "C" void kernel_launch(void* const* d_in, const int* in_sizes, int n_in,
                              void* d_out, int out_size, void* d_ws, size_t ws_size,
                              hipStream_t stream)
{
    const float* x    = (const float*)d_in[0];
    const int*   ei   = (const int*)d_in[1];
    const float* ea   = (const float*)d_in[2];
    const float* Wn1  = (const float*)d_in[3];
    const float* bn1  = (const float*)d_in[4];
    const float* We1  = (const float*)d_in[5];
    const float* be1  = (const float*)d_in[6];
    const float* Wu1  = (const float*)d_in[7];
    const float* bu1  = (const float*)d_in[8];
    const float* g1   = (const float*)d_in[9];
    const float* beta1= (const float*)d_in[10];
    const float* Wn2  = (const float*)d_in[11];
    const float* bn2  = (const float*)d_in[12];
    const float* We2  = (const float*)d_in[13];
    const float* be2  = (const float*)d_in[14];
    const float* Wu2  = (const float*)d_in[15];
    const float* bu2  = (const float*)d_in[16];
    const float* g2   = (const float*)d_in[17];
    const float* beta2= (const float*)d_in[18];

    const int* srcI = ei;
    const int* dstI = ei + NE;
    float* out = (float*)d_out;

    // ---- workspace layout
    float* invc = (float*)d_ws;                        // N
    int*   rp   = (int*)(invc + NN);                   // N+1
    int*   hist = rp + NN + 1;                         // N
    int*   psum = hist + NN;                           // 256
    int*   eperm= psum + 256;                          // E
    int*   ssrc = eperm + NE;                          // E
    uintptr_t base = ((uintptr_t)(ssrc + NE) + 15) & ~(uintptr_t)15;
    ushort* Xb    = (ushort*)base;                     // N*128 (also h1 bf16)
    ushort* meanb = Xb + (size_t)NN * 128;             // N*128
    ushort* aggEb = meanb + (size_t)NN * 128;          // N*32
    ushort* Btp1  = aggEb + (size_t)NN * 32;           // 36*128*8
    ushort* Btp2  = Btp1 + NOCT * 1024;
    float*  r1    = (float*)(Btp2 + NOCT * 1024);      // 128
    float*  r2    = r1 + 128;

    const int gemm_grid = (NN + 63) / 64;

    // ---- setup: zero hist, then merged castx|hist|prep1|prep2
    hipMemsetAsync(hist, 0, NN * sizeof(int), stream);
    init_kernel<<<CASTX_BLOCKS + HIST_BLOCKS + 2 * PREP_BLOCKS, 256, 0, stream>>>(
        x, Xb, dstI, hist,
        Wn1, bn1, We1, be1, Wu1, Btp1, r1,
        Wn2, bn2, We2, be2, Wu2, Btp2, r2);

    // ---- CSR build
    scan1_kernel<<<NBLK, 256, 0, stream>>>(hist, rp, psum);
    scan23_kernel<<<NBLK, 256, 0, stream>>>(rp, psum);
    place_kernel<<<2048, 256, 0, stream>>>(srcI, dstI, rp, hist, eperm, ssrc, NE);

    // ---- layer 1 (computes meanb + layer-invariant aggEb/invc)
    agg_kernel<true><<<(NN + 3) / 4, 256, 0, stream>>>(Xb, ea, eperm, ssrc, rp,
                                                       meanb, aggEb, invc);
    gemmF_kernel<true><<<gemm_grid, 256, 0, stream>>>(
        Xb, meanb, aggEb, invc, Btp1, r1, bu1, g1, beta1, nullptr, Xb, NN);

    // ---- layer 2 (Xb now holds h1 bf16; aggEb/invc reused)
    agg_kernel<false><<<(NN + 3) / 4, 256, 0, stream>>>(Xb, ea, eperm, ssrc, rp,
                                                        meanb, aggEb, invc);
    gemmF_kernel<false><<<gemm_grid, 256, 0, stream>>>(
        Xb, meanb, aggEb, invc, Btp2, r2, bu2, g2, beta2, out, nullptr, NN);
}

// Round 8
// 295.456 us; speedup vs baseline: 1.1784x; 1.0092x over previous
//
#include <hip/hip_runtime.h>

constexpr int NN = 100000;
constexpr int NE = 800000;
constexpr int SCAN_CHUNK = 512;
constexpr int NBLK = (NN + SCAN_CHUNK - 1) / SCAN_CHUNK;   // 196
constexpr int KTOT = 288;          // 128 (x) + 128 (mean) + 32 (aggE)
constexpr int NOCT = KTOT / 8;     // 36 k-octets

constexpr int CASTX_BLOCKS = (NN * 128 / 8 + 255) / 256;   // 6250
constexpr int HIST_BLOCKS  = 2048;
constexpr int PREP_BLOCKS  = (KTOT * 128 + 128 + 255) / 256; // 145

typedef short bf16x8 __attribute__((ext_vector_type(8)));
typedef float f32x4  __attribute__((ext_vector_type(4)));

__device__ inline ushort f2b(float f) {
    uint u = __builtin_bit_cast(uint, f);
    u += 0x7FFF + ((u >> 16) & 1);
    return (ushort)(u >> 16);
}
__device__ inline float b2f(ushort h) {
    uint u = (uint)h << 16;
    return __builtin_bit_cast(float, u);
}

// ---------------------------------------------------------------------------
// prep body: Btp[NOCT][128][8] bf16 (pre-transposed B) + r vector
__device__ inline void prep_body(int i, const float* __restrict__ Wn,
                                 const float* __restrict__ bn,
                                 const float* __restrict__ We,
                                 const float* __restrict__ be,
                                 const float* __restrict__ Wu,
                                 ushort* __restrict__ Btp, float* __restrict__ r) {
    if (i < KTOT * 128) {
        int K = i >> 7, col = i & 127;
        float v;
        if (K < 128) {
            v = Wu[(size_t)K * 128 + col];
        } else if (K < 256) {
            const float* Wubot = Wu + 128 * 128;
            float s = 0.f;
            for (int m = 0; m < 128; m++)
                s = fmaf(Wn[(K - 128) * 128 + m], Wubot[m * 128 + col], s);
            v = s;
        } else {
            const float* Wubot = Wu + 128 * 128;
            float s = 0.f;
            for (int m = 0; m < 128; m++)
                s = fmaf(We[(K - 256) * 128 + m], Wubot[m * 128 + col], s);
            v = s;
        }
        Btp[(size_t)(K >> 3) * 1024 + col * 8 + (K & 7)] = f2b(v);
    } else if (i < KTOT * 128 + 128) {
        int col = i - KTOT * 128;
        const float* Wubot = Wu + 128 * 128;
        float s = 0.f;
        for (int m = 0; m < 128; m++)
            s = fmaf(bn[m] + be[m], Wubot[m * 128 + col], s);
        r[col] = s;
    }
}

// ---------------------------------------------------------------------------
// merged setup: castx | hist | prep(layer1) | prep(layer2), by block range
__global__ __launch_bounds__(256)
void init_kernel(const float* __restrict__ x, ushort* __restrict__ Xb,
                 const int* __restrict__ dst, int* __restrict__ hist,
                 const float* __restrict__ Wn1, const float* __restrict__ bn1,
                 const float* __restrict__ We1, const float* __restrict__ be1,
                 const float* __restrict__ Wu1,
                 ushort* __restrict__ Btp1, float* __restrict__ r1,
                 const float* __restrict__ Wn2, const float* __restrict__ bn2,
                 const float* __restrict__ We2, const float* __restrict__ be2,
                 const float* __restrict__ Wu2,
                 ushort* __restrict__ Btp2, float* __restrict__ r2) {
    int b = blockIdx.x;
    if (b < CASTX_BLOCKS) {
        size_t i = ((size_t)b * 256 + threadIdx.x) * 8;
        if (i >= (size_t)NN * 128) return;
        float4 v0 = *reinterpret_cast<const float4*>(&x[i]);
        float4 v1 = *reinterpret_cast<const float4*>(&x[i + 4]);
        ushort o[8] = {f2b(v0.x), f2b(v0.y), f2b(v0.z), f2b(v0.w),
                       f2b(v1.x), f2b(v1.y), f2b(v1.z), f2b(v1.w)};
        *reinterpret_cast<bf16x8*>(&Xb[i]) = *reinterpret_cast<bf16x8*>(o);
    } else if (b < CASTX_BLOCKS + HIST_BLOCKS) {
        int bb = b - CASTX_BLOCKS;
        for (int i = bb * 256 + threadIdx.x; i < NE; i += HIST_BLOCKS * 256)
            atomicAdd(&hist[dst[i]], 1);
    } else if (b < CASTX_BLOCKS + HIST_BLOCKS + PREP_BLOCKS) {
        int i = (b - CASTX_BLOCKS - HIST_BLOCKS) * 256 + threadIdx.x;
        prep_body(i, Wn1, bn1, We1, be1, Wu1, Btp1, r1);
    } else {
        int i = (b - CASTX_BLOCKS - HIST_BLOCKS - PREP_BLOCKS) * 256 + threadIdx.x;
        prep_body(i, Wn2, bn2, We2, be2, Wu2, Btp2, r2);
    }
}

// ---------------------------------------------------------------------------
// scan1: per-chunk exclusive scan + chunk totals
__global__ __launch_bounds__(256)
void scan1_kernel(const int* __restrict__ hist, int* __restrict__ rp,
                  int* __restrict__ psum) {
    __shared__ int wsum[4];
    const int b = blockIdx.x, t = threadIdx.x;
    const int i0 = b * SCAN_CHUNK + 2 * t;
    int v0 = (i0     < NN) ? hist[i0]     : 0;
    int v1 = (i0 + 1 < NN) ? hist[i0 + 1] : 0;
    const int ts = v0 + v1;
    const int lane = t & 63, wid = t >> 6;
    int x = ts;
#pragma unroll
    for (int d = 1; d < 64; d <<= 1) {
        int n = __shfl_up(x, d, 64);
        if (lane >= d) x += n;
    }
    if (lane == 63) wsum[wid] = x;
    __syncthreads();
    int woff = (wid > 0 ? wsum[0] : 0) + (wid > 1 ? wsum[1] : 0) +
               (wid > 2 ? wsum[2] : 0);
    int incl = x + woff;
    int excl = incl - ts;
    if (i0     < NN) rp[i0]     = excl;
    if (i0 + 1 < NN) rp[i0 + 1] = excl + v0;
    if (t == 255) psum[b] = incl;
}

// scan2+3 merged: each block reduces psum[0..b) itself, then offsets its chunk
__global__ __launch_bounds__(256)
void scan23_kernel(int* __restrict__ rp, const int* __restrict__ psum) {
    __shared__ int wred[4];
    const int b = blockIdx.x, t = threadIdx.x;
    int val = (t < b) ? psum[t] : 0;    // b <= NBLK-1 < 256
    const int lane = t & 63, wid = t >> 6;
#pragma unroll
    for (int m = 1; m < 64; m <<= 1) val += __shfl_xor(val, m, 64);
    if (lane == 0) wred[wid] = val;
    __syncthreads();
    const int off = wred[0] + wred[1] + wred[2] + wred[3];
    const int i0 = b * SCAN_CHUNK + 2 * t;
    if (i0     < NN) rp[i0]     += off;
    if (i0 + 1 < NN) rp[i0 + 1] += off;
    if (b == 0 && t == 0) rp[NN] = NE;
}

// ---------------------------------------------------------------------------
// placement; hist counted DOWN to zero (no separate fill array)
__global__ __launch_bounds__(256)
void place_kernel(const int* __restrict__ src, const int* __restrict__ dst,
                  const int* __restrict__ rp, int* __restrict__ hist,
                  int* __restrict__ eperm, int* __restrict__ ssrc, int E) {
    for (int e = blockIdx.x * blockDim.x + threadIdx.x; e < E;
         e += gridDim.x * blockDim.x) {
        int d = dst[e];
        int pos = rp[d] + atomicSub(&hist[d], 1) - 1;
        eperm[pos] = e;
        ssrc[pos]  = src[e];
    }
}

// ---------------------------------------------------------------------------
// CSR aggregation, edge-pair scheme (round-6 measured-best):
// lanes 0-31 handle even edge of pair, 32-63 odd; 8 edges per iteration.
template<bool DO_EA>
__global__ __launch_bounds__(256)
void agg_kernel(const ushort* __restrict__ Xb, const float* __restrict__ ea,
                const int* __restrict__ eperm, const int* __restrict__ ssrc,
                const int* __restrict__ rp,
                ushort* __restrict__ meanb, ushort* __restrict__ aggEb,
                float* __restrict__ invc) {
    const int wid  = __builtin_amdgcn_readfirstlane(threadIdx.x >> 6);
    const int lane = threadIdx.x & 63;
    const int v = blockIdx.x * 4 + wid;
    if (v >= NN) return;
    const int beg = __builtin_amdgcn_readfirstlane(rp[v]);
    const int end = __builtin_amdgcn_readfirstlane(rp[v + 1]);
    const int half = lane >> 5;
    const int l32  = lane & 31;

    float a0 = 0.f, a1 = 0.f, a2 = 0.f, a3 = 0.f;
    float aE = 0.f;
    int i = beg;
    // ---- 8 edges per iteration (4 pair-loads in flight)
    for (; i + 7 < end; i += 8) {
        int s0 = __builtin_amdgcn_readfirstlane(ssrc[i]);
        int s1 = __builtin_amdgcn_readfirstlane(ssrc[i + 1]);
        int s2 = __builtin_amdgcn_readfirstlane(ssrc[i + 2]);
        int s3 = __builtin_amdgcn_readfirstlane(ssrc[i + 3]);
        int s4 = __builtin_amdgcn_readfirstlane(ssrc[i + 4]);
        int s5 = __builtin_amdgcn_readfirstlane(ssrc[i + 5]);
        int s6 = __builtin_amdgcn_readfirstlane(ssrc[i + 6]);
        int s7 = __builtin_amdgcn_readfirstlane(ssrc[i + 7]);
        int sA = half ? s1 : s0, sB = half ? s3 : s2;
        int sC = half ? s5 : s4, sD = half ? s7 : s6;
        uint2 qA = *reinterpret_cast<const uint2*>(Xb + (size_t)sA * 128 + l32 * 4);
        uint2 qB = *reinterpret_cast<const uint2*>(Xb + (size_t)sB * 128 + l32 * 4);
        uint2 qC = *reinterpret_cast<const uint2*>(Xb + (size_t)sC * 128 + l32 * 4);
        uint2 qD = *reinterpret_cast<const uint2*>(Xb + (size_t)sD * 128 + l32 * 4);
        if (DO_EA) {
            int e0 = __builtin_amdgcn_readfirstlane(eperm[i]);
            int e1 = __builtin_amdgcn_readfirstlane(eperm[i + 1]);
            int e2 = __builtin_amdgcn_readfirstlane(eperm[i + 2]);
            int e3 = __builtin_amdgcn_readfirstlane(eperm[i + 3]);
            int e4 = __builtin_amdgcn_readfirstlane(eperm[i + 4]);
            int e5 = __builtin_amdgcn_readfirstlane(eperm[i + 5]);
            int e6 = __builtin_amdgcn_readfirstlane(eperm[i + 6]);
            int e7 = __builtin_amdgcn_readfirstlane(eperm[i + 7]);
            int eA = half ? e1 : e0, eB = half ? e3 : e2;
            int eC = half ? e5 : e4, eD = half ? e7 : e6;
            float fA = ea[(size_t)eA * 32 + l32];
            float fB = ea[(size_t)eB * 32 + l32];
            float fC = ea[(size_t)eC * 32 + l32];
            float fD = ea[(size_t)eD * 32 + l32];
            aE += (fA + fB) + (fC + fD);
        }
        a0 += (b2f((ushort)qA.x) + b2f((ushort)qB.x)) +
              (b2f((ushort)qC.x) + b2f((ushort)qD.x));
        a1 += (b2f((ushort)(qA.x >> 16)) + b2f((ushort)(qB.x >> 16))) +
              (b2f((ushort)(qC.x >> 16)) + b2f((ushort)(qD.x >> 16)));
        a2 += (b2f((ushort)qA.y) + b2f((ushort)qB.y)) +
              (b2f((ushort)qC.y) + b2f((ushort)qD.y));
        a3 += (b2f((ushort)(qA.y >> 16)) + b2f((ushort)(qB.y >> 16))) +
              (b2f((ushort)(qC.y >> 16)) + b2f((ushort)(qD.y >> 16)));
    }
    // ---- 4-edge step
    if (i + 3 < end) {
        int s0 = __builtin_amdgcn_readfirstlane(ssrc[i]);
        int s1 = __builtin_amdgcn_readfirstlane(ssrc[i + 1]);
        int s2 = __builtin_amdgcn_readfirstlane(ssrc[i + 2]);
        int s3 = __builtin_amdgcn_readfirstlane(ssrc[i + 3]);
        int sA = half ? s1 : s0, sB = half ? s3 : s2;
        uint2 qA = *reinterpret_cast<const uint2*>(Xb + (size_t)sA * 128 + l32 * 4);
        uint2 qB = *reinterpret_cast<const uint2*>(Xb + (size_t)sB * 128 + l32 * 4);
        if (DO_EA) {
            int e0 = __builtin_amdgcn_readfirstlane(eperm[i]);
            int e1 = __builtin_amdgcn_readfirstlane(eperm[i + 1]);
            int e2 = __builtin_amdgcn_readfirstlane(eperm[i + 2]);
            int e3 = __builtin_amdgcn_readfirstlane(eperm[i + 3]);
            int eA = half ? e1 : e0, eB = half ? e3 : e2;
            aE += ea[(size_t)eA * 32 + l32] + ea[(size_t)eB * 32 + l32];
        }
        a0 += b2f((ushort)qA.x) + b2f((ushort)qB.x);
        a1 += b2f((ushort)(qA.x >> 16)) + b2f((ushort)(qB.x >> 16));
        a2 += b2f((ushort)qA.y) + b2f((ushort)qB.y);
        a3 += b2f((ushort)(qA.y >> 16)) + b2f((ushort)(qB.y >> 16));
        i += 4;
    }
    // ---- 2-edge step
    if (i + 1 < end) {
        int s0 = __builtin_amdgcn_readfirstlane(ssrc[i]);
        int s1 = __builtin_amdgcn_readfirstlane(ssrc[i + 1]);
        int sA = half ? s1 : s0;
        uint2 qA = *reinterpret_cast<const uint2*>(Xb + (size_t)sA * 128 + l32 * 4);
        if (DO_EA) {
            int e0 = __builtin_amdgcn_readfirstlane(eperm[i]);
            int e1 = __builtin_amdgcn_readfirstlane(eperm[i + 1]);
            int eA = half ? e1 : e0;
            aE += ea[(size_t)eA * 32 + l32];
        }
        a0 += b2f((ushort)qA.x);
        a1 += b2f((ushort)(qA.x >> 16));
        a2 += b2f((ushort)qA.y);
        a3 += b2f((ushort)(qA.y >> 16));
        i += 2;
    }
    // ---- 1-edge tail (half 0 only)
    if (i < end) {
        int s0 = __builtin_amdgcn_readfirstlane(ssrc[i]);
        if (half == 0) {
            uint2 qA = *reinterpret_cast<const uint2*>(Xb + (size_t)s0 * 128 + l32 * 4);
            a0 += b2f((ushort)qA.x);
            a1 += b2f((ushort)(qA.x >> 16));
            a2 += b2f((ushort)qA.y);
            a3 += b2f((ushort)(qA.y >> 16));
            if (DO_EA) {
                int e0 = __builtin_amdgcn_readfirstlane(eperm[i]);
                aE += ea[(size_t)e0 * 32 + l32];
            }
        }
    }
    // ---- combine halves
    a0 += __shfl_xor(a0, 32, 64);
    a1 += __shfl_xor(a1, 32, 64);
    a2 += __shfl_xor(a2, 32, 64);
    a3 += __shfl_xor(a3, 32, 64);
    if (DO_EA) aE += __shfl_xor(aE, 32, 64);

    float inv = (end > beg) ? 1.0f / (float)(end - beg) : 0.0f;
    if (half == 0) {
        uint lo = (uint)f2b(a0 * inv) | ((uint)f2b(a1 * inv) << 16);
        uint hi = (uint)f2b(a2 * inv) | ((uint)f2b(a3 * inv) << 16);
        *reinterpret_cast<uint2*>(meanb + (size_t)v * 128 + l32 * 4) =
            make_uint2(lo, hi);
        if (DO_EA) aggEb[(size_t)v * 32 + l32] = f2b(aE * inv);
    }
    if (DO_EA && lane == 0) invc[v] = inv;
}

// ---------------------------------------------------------------------------
// fused MFMA GEMM, 64-row tile (measured-best config):
// C = LN(relu(Abig @ B + bu + has*r), g, beta)
template<bool OUT_BF16>
__global__ __launch_bounds__(256)
void gemmF_kernel(const ushort* __restrict__ Xb, const ushort* __restrict__ meanb,
                  const ushort* __restrict__ aggEb, const float* __restrict__ invc,
                  const ushort* __restrict__ Btp, const float* __restrict__ r,
                  const float* __restrict__ bu, const float* __restrict__ g,
                  const float* __restrict__ beta,
                  float* __restrict__ Cf, ushort* __restrict__ Cb, int M) {
    __shared__ ushort Als[4][64][8];
    __shared__ ushort Bls[4][128][8];
    __shared__ float ps[2][64], ps2[2][64];

    const int tid = threadIdx.x;
    const int wid = tid >> 6, lane = tid & 63;
    const int wr = wid >> 1, wc = wid & 1;
    const int lo4 = lane >> 4, li = lane & 15;
    const int brow = blockIdx.x * 64;

    f32x4 acc[2][4];
#pragma unroll
    for (int fr = 0; fr < 2; fr++)
#pragma unroll
        for (int fc = 0; fc < 4; fc++) acc[fr][fc] = (f32x4)0.f;

    const int arow = tid & 63;
    const int akc  = tid >> 6;
    const int grow = brow + arow;

    for (int step = 0; step < 9; step++) {
        {
            int kg = step * 4 + akc;
            bf16x8 v = (bf16x8)0;
            if (grow < M) {
                if (kg < 16)
                    v = *reinterpret_cast<const bf16x8*>(Xb + (size_t)grow * 128 + kg * 8);
                else if (kg < 32)
                    v = *reinterpret_cast<const bf16x8*>(meanb + (size_t)grow * 128 + (kg - 16) * 8);
                else
                    v = *reinterpret_cast<const bf16x8*>(aggEb + (size_t)grow * 32 + (kg - 32) * 8);
            }
            *reinterpret_cast<bf16x8*>(&Als[akc][arow][0]) = v;
        }
#pragma unroll
        for (int h = 0; h < 2; h++) {
            int u = tid + h * 256;
            int kcl = u >> 7, col = u & 127;
            *reinterpret_cast<bf16x8*>(&Bls[kcl][col][0]) =
                *reinterpret_cast<const bf16x8*>(
                    Btp + ((size_t)(step * 4 + kcl) * 128 + col) * 8);
        }
        __syncthreads();

        bf16x8 a0 = *reinterpret_cast<const bf16x8*>(&Als[lo4][wr * 32 + li][0]);
        bf16x8 a1 = *reinterpret_cast<const bf16x8*>(&Als[lo4][wr * 32 + 16 + li][0]);
#pragma unroll
        for (int fc = 0; fc < 4; fc++) {
            bf16x8 b = *reinterpret_cast<const bf16x8*>(&Bls[lo4][wc * 64 + fc * 16 + li][0]);
            acc[0][fc] = __builtin_amdgcn_mfma_f32_16x16x32_bf16(a0, b, acc[0][fc], 0, 0, 0);
            acc[1][fc] = __builtin_amdgcn_mfma_f32_16x16x32_bf16(a1, b, acc[1][fc], 0, 0, 0);
        }
        __syncthreads();
    }

    float bu8[4], r8[4], g8[4], be8[4];
#pragma unroll
    for (int fc = 0; fc < 4; fc++) {
        int col = wc * 64 + fc * 16 + li;
        bu8[fc] = bu[col]; r8[fc] = r[col]; g8[fc] = g[col]; be8[fc] = beta[col];
    }

    float sv[2][4], s2v[2][4];
#pragma unroll
    for (int fr = 0; fr < 2; fr++)
#pragma unroll
        for (int j = 0; j < 4; j++) {
            int gr = brow + wr * 32 + fr * 16 + lo4 * 4 + j;
            float hv = 0.f;
            if (gr < M) hv = (invc[gr] > 0.f) ? 1.f : 0.f;
            float s = 0.f, s2 = 0.f;
#pragma unroll
            for (int fc = 0; fc < 4; fc++) {
                float val = acc[fr][fc][j] + bu8[fc] + hv * r8[fc];
                val = fmaxf(val, 0.f);
                acc[fr][fc][j] = val;
                s += val; s2 += val * val;
            }
#pragma unroll
            for (int m = 1; m < 16; m <<= 1) {
                s  += __shfl_xor(s, m, 64);
                s2 += __shfl_xor(s2, m, 64);
            }
            sv[fr][j] = s; s2v[fr][j] = s2;
        }

    if (li == 0) {
#pragma unroll
        for (int fr = 0; fr < 2; fr++)
#pragma unroll
            for (int j = 0; j < 4; j++) {
                int row64 = wr * 32 + fr * 16 + lo4 * 4 + j;
                ps[wc][row64]  = sv[fr][j];
                ps2[wc][row64] = s2v[fr][j];
            }
    }
    __syncthreads();

#pragma unroll
    for (int fr = 0; fr < 2; fr++)
#pragma unroll
        for (int j = 0; j < 4; j++) {
            int row64 = wr * 32 + fr * 16 + lo4 * 4 + j;
            int gr = brow + row64;
            float s  = sv[fr][j]  + ps[1 - wc][row64];
            float s2 = s2v[fr][j] + ps2[1 - wc][row64];
            float mean = s * (1.0f / 128.0f);
            float var  = s2 * (1.0f / 128.0f) - mean * mean;
            float rstd = rsqrtf(var + 1e-5f);
            if (gr < M) {
#pragma unroll
                for (int fc = 0; fc < 4; fc++) {
                    int col = wc * 64 + fc * 16 + li;
                    float o = (acc[fr][fc][j] - mean) * rstd * g8[fc] + be8[fc];
                    if (OUT_BF16) Cb[(size_t)gr * 128 + col] = f2b(o);
                    else          Cf[(size_t)gr * 128 + col] = o;
                }
            }
        }
}

// ---------------------------------------------------------------------------
extern "C" void kernel_launch(void* const* d_in, const int* in_sizes, int n_in,
                              void* d_out, int out_size, void* d_ws, size_t ws_size,
                              hipStream_t stream)
{
    const float* x    = (const float*)d_in[0];
    const int*   ei   = (const int*)d_in[1];
    const float* ea   = (const float*)d_in[2];
    const float* Wn1  = (const float*)d_in[3];
    const float* bn1  = (const float*)d_in[4];
    const float* We1  = (const float*)d_in[5];
    const float* be1  = (const float*)d_in[6];
    const float* Wu1  = (const float*)d_in[7];
    const float* bu1  = (const float*)d_in[8];
    const float* g1   = (const float*)d_in[9];
    const float* beta1= (const float*)d_in[10];
    const float* Wn2  = (const float*)d_in[11];
    const float* bn2  = (const float*)d_in[12];
    const float* We2  = (const float*)d_in[13];
    const float* be2  = (const float*)d_in[14];
    const float* Wu2  = (const float*)d_in[15];
    const float* bu2  = (const float*)d_in[16];
    const float* g2   = (const float*)d_in[17];
    const float* beta2= (const float*)d_in[18];

    const int* srcI = ei;
    const int* dstI = ei + NE;
    float* out = (float*)d_out;

    // ---- workspace layout
    float* invc = (float*)d_ws;                        // N
    int*   rp   = (int*)(invc + NN);                   // N+1
    int*   hist = rp + NN + 1;                         // N
    int*   psum = hist + NN;                           // 256
    int*   eperm= psum + 256;                          // E
    int*   ssrc = eperm + NE;                          // E
    uintptr_t base = ((uintptr_t)(ssrc + NE) + 15) & ~(uintptr_t)15;
    ushort* Xb    = (ushort*)base;                     // N*128 (also h1 bf16)
    ushort* meanb = Xb + (size_t)NN * 128;             // N*128
    ushort* aggEb = meanb + (size_t)NN * 128;          // N*32
    ushort* Btp1  = aggEb + (size_t)NN * 32;           // 36*128*8
    ushort* Btp2  = Btp1 + NOCT * 1024;
    float*  r1    = (float*)(Btp2 + NOCT * 1024);      // 128
    float*  r2    = r1 + 128;

    const int gemm_grid = (NN + 63) / 64;

    // ---- setup: zero hist, then merged castx|hist|prep1|prep2
    hipMemsetAsync(hist, 0, NN * sizeof(int), stream);
    init_kernel<<<CASTX_BLOCKS + HIST_BLOCKS + 2 * PREP_BLOCKS, 256, 0, stream>>>(
        x, Xb, dstI, hist,
        Wn1, bn1, We1, be1, Wu1, Btp1, r1,
        Wn2, bn2, We2, be2, Wu2, Btp2, r2);

    // ---- CSR build
    scan1_kernel<<<NBLK, 256, 0, stream>>>(hist, rp, psum);
    scan23_kernel<<<NBLK, 256, 0, stream>>>(rp, psum);
    place_kernel<<<2048, 256, 0, stream>>>(srcI, dstI, rp, hist, eperm, ssrc, NE);

    // ---- layer 1 (computes meanb + layer-invariant aggEb/invc)
    agg_kernel<true><<<(NN + 3) / 4, 256, 0, stream>>>(Xb, ea, eperm, ssrc, rp,
                                                       meanb, aggEb, invc);
    gemmF_kernel<true><<<gemm_grid, 256, 0, stream>>>(
        Xb, meanb, aggEb, invc, Btp1, r1, bu1, g1, beta1, nullptr, Xb, NN);

    // ---- layer 2 (Xb now holds h1 bf16; aggEb/invc reused)
    agg_kernel<false><<<(NN + 3) / 4, 256, 0, stream>>>(Xb, ea, eperm, ssrc, rp,
                                                        meanb, aggEb, invc);
    gemmF_kernel<false><<<gemm_grid, 256, 0, stream>>>(
        Xb, meanb, aggEb, invc, Btp2, r2, bu2, g2, beta2, out, nullptr, NN);
}